// Round 6
// baseline (164.691 us; speedup 1.0000x reference)
//
#include <hip/hip_runtime.h>
#include <hip/hip_bf16.h>

#define TGT 256
#define BSZ 8
#define E   256
#define SRC 4096

typedef __attribute__((ext_vector_type(8))) short           bf16x8;
typedef __attribute__((ext_vector_type(4))) float           f32x4;
typedef __attribute__((ext_vector_type(4))) float           f4;
typedef __attribute__((ext_vector_type(8))) unsigned short  u16x8;
typedef __attribute__((ext_vector_type(4))) unsigned short  u16x4;

__device__ inline unsigned short f2b(float x) {
    union { __hip_bfloat16 h; unsigned short u; } cv;
    cv.h = __float2bfloat16(x);
    return cv.u;
}

__device__ inline bf16x8 cvt8v(const float* __restrict__ p) {
    f4 lo = *(const f4*)p;
    f4 hi = *(const f4*)(p + 4);
    bf16x8 r;
    #pragma unroll
    for (int j = 0; j < 4; ++j) { r[j] = (short)f2b(lo[j]); r[4 + j] = (short)f2b(hi[j]); }
    return r;
}

// ---------------------------------------------------------------------------
// prep_w: W(E,E) fp32 -> wf in B-fragment order (bf16), ONCE.
//   wf[((et*8 + ks)*64 + lane)*8 + j] = W[et*16+(lane&15)][ks*32+(lane>>4)*8+j]
// ---------------------------------------------------------------------------
__global__ __launch_bounds__(128) void prep_w(
    const float* __restrict__ wgt, unsigned short* __restrict__ wf)
{
    int o    = blockIdx.x * 128 + threadIdx.x;   // 0..8191
    int et   = o >> 9;
    int ks   = (o >> 6) & 7;
    int lane = o & 63;
    int quad = lane >> 4, l15 = lane & 15;
    bf16x8 v = cvt8v(wgt + (size_t)(et * 16 + l15) * E + ks * 32 + quad * 8);
    *(bf16x8*)&wf[(size_t)o * 8] = v;
}

// ---------------------------------------------------------------------------
// prep_vw: grid (128, 9) x 256 thr. ONE barrier, no LDS repack.
//  by<8 : VW[s,n] = sum_e V[s,b,e]*W[n,e] over a 32-row s-chunk.
//    4 waves: wave w -> m-tile mt=w>>1 (16 rows), et half (w&1)*8.
//    D fragments are stored DIRECTLY to vwf in B-frag order: for global
//    k = sc32*32 + mt*16 + quad*4 + r the vwf coords are
//      ks = sc32, lane' = (mt*2 + (quad>>1))*16 + l15, j = (quad&1)*4 + r
//    -> r is the fastest index => one u16x4 (8B) store per (e).
//  by==8: out0 init — out0[t,b,e] = bias[e] (gemm1 atomically accumulates).
// ---------------------------------------------------------------------------
__global__ __launch_bounds__(256, 4) void prep_vw(
    const float* __restrict__ value, const unsigned short* __restrict__ wf,
    const float* __restrict__ bias,
    unsigned short* __restrict__ vwf, float* __restrict__ out0)
{
    const int tid = threadIdx.x;

    if (blockIdx.y == 8) {               // ---- bias-init of out0 (2 MB)
        #pragma unroll
        for (int s = 0; s < 4; ++s) {
            int f4i = s * 32768 + blockIdx.x * 256 + tid;   // 0..131071
            *(f4*)(out0 + (size_t)f4i * 4) = *(const f4*)(bias + (f4i & 63) * 4);
        }
        return;
    }

    __shared__ unsigned short tile[32 * 264];   // 16.9 KB
    const int sc32 = blockIdx.x;                // 0..127 (32-row s-chunk)
    const int b    = blockIdx.y;
    const int s0   = sc32 * 32;

    // ---- stage V chunk (32 s-rows x 256 e) -> bf16 LDS (coalesced)
    #pragma unroll
    for (int i = 0; i < 8; ++i) {
        int lin = i * 256 + tid;                // 0..2047
        int row = lin >> 6;                     // s-local 0..31
        int c4  = lin & 63;                     // e float4 idx
        f4 v = *(const f4*)(value + (size_t)(s0 + row) * (BSZ * E)
                                  + (size_t)b * E + c4 * 4);
        u16x4 pk;
        #pragma unroll
        for (int j = 0; j < 4; ++j) pk[j] = f2b(v[j]);
        *(u16x4*)&tile[row * 264 + c4 * 4] = pk;
    }
    __syncthreads();                            // the ONLY barrier

    const int w    = tid >> 6;                  // wave 0..3
    const int lane = tid & 63;
    const int quad = lane >> 4;
    const int l15  = lane & 15;
    const int mt   = w >> 1;                    // m-tile 0..1 (16 s-rows)
    const int et0  = (w & 1) * 8;               // et half

    // A-frags: m = s-local (mt*16 + l15), k = e
    bf16x8 a[8];
    #pragma unroll
    for (int ks = 0; ks < 8; ++ks)
        a[ks] = *(const bf16x8*)&tile[(mt * 16 + l15) * 264 + ks * 32 + quad * 8];

    // ---- VW = Vtile @ W^T ; ks-outer: 8 batched wf loads + 8 indep MFMAs
    const unsigned short* bfw = wf + ((size_t)et0 * 8) * 512 + (size_t)lane * 8;
    f32x4 acc[8] = {};
    #pragma unroll
    for (int ks = 0; ks < 8; ++ks) {
        bf16x8 bb[8];
        #pragma unroll
        for (int e = 0; e < 8; ++e)
            bb[e] = *(const bf16x8*)(bfw + (size_t)(e * 8 + ks) * 512);
        #pragma unroll
        for (int e = 0; e < 8; ++e)
            acc[e] = __builtin_amdgcn_mfma_f32_16x16x32_bf16(a[ks], bb[e], acc[e], 0, 0, 0);
    }

    // ---- direct B-frag store: one 8B u16x4 per (e)
    const int lp = (mt * 2 + (quad >> 1)) * 16 + l15;   // lane' in B-frag order
    const int j0 = (quad & 1) * 4;
    #pragma unroll
    for (int e = 0; e < 8; ++e) {
        u16x4 pk;
        #pragma unroll
        for (int r = 0; r < 4; ++r) pk[r] = f2b(acc[e][r]);
        *(u16x4*)&vwf[((((size_t)b * 16 + et0 + e) * 128 + sc32) * 64 + lp) * 8 + j0] = pk;
    }
}

// ---------------------------------------------------------------------------
// gemm1: per block (b, tt, kc): acc = M_b[16t, 512k] @ VW_b[512k, 256n],
// then atomicAdd into out0.
//  - mask loads and out1 stores are NONTEMPORAL: they streamed 32 MB through
//    each XCD's 4 MB L2 and evicted the 2 MB vwf b-slice, forcing 134 MB of
//    B-frag re-reads to L3. NT keeps vwf L2-resident.
//  - 256-thr blocks (16 t-rows) -> 1024 blocks = 4/CU for phase overlap.
// ---------------------------------------------------------------------------
#define GP 520   // A pitch u16: 1040 B rows (16B-aligned)

__global__ __launch_bounds__(256, 4) void gemm1(
    const float* __restrict__ mask,
    const unsigned short* __restrict__ vwf,
    float* __restrict__ out1,
    float* __restrict__ out0)
{
    __shared__ unsigned short As[16 * GP];      // 16.6 KB
    const int bx  = blockIdx.x;
    const int b   = bx & 7;                     // XCD swizzle: same-b -> same XCD
    const int tt  = (bx >> 3) & 15;             // 0..15, t-tile of 16 rows
    const int kc  = bx >> 7;                    // 0..7, K-chunk 512
    const int t0  = tt * 16;
    const int k0  = kc * 512;
    const int tid = threadIdx.x;
    const int w    = tid >> 6;
    const int lane = tid & 63;
    const int quad = lane >> 4;
    const int l15  = lane & 15;

    const float* mbase = mask + (size_t)b * TGT * SRC + (size_t)t0 * SRC + k0;
    float*       obase = out1 + (size_t)b * TGT * SRC + (size_t)t0 * SRC + k0;

    // ---- stage tile: thread -> row tid>>4 (0..15), f4-cols (tid&15)+j*16
    const int srow = tid >> 4;
    const int sc4  = tid & 15;
    f4 mv[8];
    #pragma unroll
    for (int j = 0; j < 8; ++j)
        mv[j] = __builtin_nontemporal_load(
                    (const f4*)(mbase + (size_t)srow * SRC + (sc4 + j * 16) * 4));
    #pragma unroll
    for (int j = 0; j < 8; ++j) {
        u16x4 pk;
        #pragma unroll
        for (int t = 0; t < 4; ++t) pk[t] = f2b(mv[j][t]);
        *(u16x4*)&As[srow * GP + (sc4 + j * 16) * 4] = pk;
    }
    __syncthreads();

    // out1 copy after the barrier: NT stores retire under the MFMA loop
    #pragma unroll
    for (int j = 0; j < 8; ++j)
        __builtin_nontemporal_store(
            mv[j], (f4*)(obase + (size_t)srow * SRC + (sc4 + j * 16) * 4));

    // wave w owns e' tiles et = w*4 .. w*4+3 (64 n-cols)
    const unsigned short* bfr = vwf + (((size_t)b * 16 + (size_t)w * 4) * 128
                                       + (size_t)kc * 16) * 512 + (size_t)lane * 8;

    f32x4 acc[4] = {};
    #pragma unroll 4
    for (int q = 0; q < 16; ++q) {
        bf16x8 a0 = *(const bf16x8*)&As[l15 * GP + q * 32 + quad * 8];
        bf16x8 B0 = *(const bf16x8*)(bfr + ((size_t)0 * 128 + q) * 512);
        bf16x8 B1 = *(const bf16x8*)(bfr + ((size_t)1 * 128 + q) * 512);
        bf16x8 B2 = *(const bf16x8*)(bfr + ((size_t)2 * 128 + q) * 512);
        bf16x8 B3 = *(const bf16x8*)(bfr + ((size_t)3 * 128 + q) * 512);
        acc[0] = __builtin_amdgcn_mfma_f32_16x16x32_bf16(a0, B0, acc[0], 0, 0, 0);
        acc[1] = __builtin_amdgcn_mfma_f32_16x16x32_bf16(a0, B1, acc[1], 0, 0, 0);
        acc[2] = __builtin_amdgcn_mfma_f32_16x16x32_bf16(a0, B2, acc[2], 0, 0, 0);
        acc[3] = __builtin_amdgcn_mfma_f32_16x16x32_bf16(a0, B3, acc[3], 0, 0, 0);
    }

    // ---- epilogue: direct atomic accumulation into out0[t, b, e']
    // D layout: col = lane&15 (n), row = quad*4 + reg (m)  [verified m89/m91]
    #pragma unroll
    for (int e = 0; e < 4; ++e) {
        int ecol = (w * 4 + e) * 16 + l15;
        #pragma unroll
        for (int r = 0; r < 4; ++r) {
            int t = t0 + quad * 4 + r;
            atomicAdd(out0 + (size_t)t * (BSZ * E) + (size_t)b * E + ecol, acc[e][r]);
        }
    }
}

// ---------------------------------------------------------------------------
extern "C" void kernel_launch(void* const* d_in, const int* in_sizes, int n_in,
                              void* d_out, int out_size, void* d_ws, size_t ws_size,
                              hipStream_t stream)
{
    // inputs: 0=query(unused) 1=key(unused) 2=value 3=proposal_mask 4=W 5=bias
    const float* value = (const float*)d_in[2];
    const float* mask  = (const float*)d_in[3];
    const float* wgt   = (const float*)d_in[4];
    const float* bias  = (const float*)d_in[5];

    float* out0 = (float*)d_out;                              // (256,8,256)
    float* out1 = (float*)d_out + (size_t)TGT * BSZ * E;      // (8,256,4096)

    // ws layout: vwf bf16 16.8MB | wf bf16 128KB
    unsigned short* vwf = (unsigned short*)d_ws;
    unsigned short* wf  = vwf + (size_t)BSZ * E * SRC;

    prep_w <<<64, 128, 0, stream>>>(wgt, wf);
    prep_vw<<<dim3(128, 9), 256, 0, stream>>>(value, wf, bias, vwf, out0);
    gemm1  <<<1024, 256, 0, stream>>>(mask, vwf, out1, out0);
}